// Round 8
// baseline (518.829 us; speedup 1.0000x reference)
//
#include <hip/hip_runtime.h>
#include <stdint.h>

#define TT 50
#define NSTEP 49
#define NBATCH 4096
#define SS 100
#define HH 256
#define K1 128      // padded K for GEMM1 (S=100 -> 128)
#define MROWS 16
#define NBLK 256
#define NTHR 1024   // 16 waves -> 4 waves/SIMD

typedef short bf16x8 __attribute__((ext_vector_type(8)));
typedef float f32x4 __attribute__((ext_vector_type(4)));
typedef float f32x2 __attribute__((ext_vector_type(2)));

#define MFMA(a, b, c) __builtin_amdgcn_mfma_f32_16x16x32_bf16((a), (b), (c), 0, 0, 0)

// Fragment-linear weight layouts: [t][nt][ks][lane][8 bf16], 16B per lane.
#define W1G_OFF(t, nt, ks) ((((size_t)(t) * 16 + (nt)) * 4 + (ks)) * 512)
#define W2G_OFF(t, nt, ks) ((((size_t)(t) * 16 + (nt)) * 8 + (ks)) * 512)
#define WOG_OFF(t, nt, ks) ((((size_t)(t) * 8 + (nt)) * 8 + (ks)) * 512)
#define N_W1G W1G_OFF(TT, 0, 0)
#define N_W2G W2G_OFF(TT, 0, 0)
#define N_WOG WOG_OFF(TT, 0, 0)

// LDS-only barrier: waits ds ops but does NOT drain vmcnt.
__device__ __forceinline__ void bar_lds() {
  __asm__ volatile("s_waitcnt lgkmcnt(0)\n\ts_barrier" ::: "memory");
}

__device__ __forceinline__ short f2b(float f) {
  union { float f; uint32_t u; } v;
  v.f = f;
  return (short)((v.u + 0x7FFFu + ((v.u >> 16) & 1u)) >> 16);
}

__device__ __forceinline__ bf16x8 cvt8(const float* __restrict__ p) {
  bf16x8 r;
#pragma unroll
  for (int j = 0; j < 8; ++j) r[j] = f2b(p[j]);
  return r;
}

__device__ __forceinline__ bf16x8 ldpad(const float* __restrict__ rowp, int k, int kmax) {
  bf16x8 r;
#pragma unroll
  for (int j = 0; j < 8; ++j) {
    int kk = k + j;
    r[j] = (kk < kmax) ? f2b(rowp[kk]) : (short)0;
  }
  return r;
}

__global__ void zero_out(float* out) {
  if (threadIdx.x == 0 && blockIdx.x == 0) out[0] = 0.f;
}

// Coalesced prep: stage a 16-row chunk in LDS (contiguous global reads),
// emit fragment-linear bf16 (contiguous global writes).
__global__ __launch_bounds__(256) void prep(
    const float* __restrict__ W1, const float* __restrict__ b1,
    const float* __restrict__ W2, const float* __restrict__ Wo,
    short* __restrict__ W1g, short* __restrict__ W2g, short* __restrict__ Wog,
    float* __restrict__ out) {
  __shared__ float tile[16 * 264];
  const int tid = threadIdx.x;
  const int wg = blockIdx.x;
  if (wg == 0 && tid == 0) out[0] = 0.f;
  if (wg < 800) {                     // W1: wg = t*16 + nt
    const int t = wg >> 4, nt = wg & 15;
    const float* src = W1 + ((size_t)t * HH + nt * 16) * SS;
    const float* bsrc = b1 + t * HH + nt * 16;
    for (int i = tid; i < 16 * K1; i += 256) {
      int m = i >> 7, k = i & 127;
      float v = (k < SS) ? src[m * SS + k] : (k == SS ? bsrc[m] : 0.f);
      tile[m * 264 + k] = v;
    }
    __syncthreads();
    {
      int ks = tid >> 6, lane = tid & 63;
      int qq = lane >> 4, cc = lane & 15;
      bf16x8 v;
#pragma unroll
      for (int j = 0; j < 8; ++j) v[j] = f2b(tile[cc * 264 + ks * 32 + qq * 8 + j]);
      *(bf16x8*)&W1g[W1G_OFF(t, nt, ks) + lane * 8] = v;
    }
  } else if (wg < 1600) {             // W2
    const int h = wg - 800;
    const int t = h >> 4, nt = h & 15;
    const float* src = W2 + ((size_t)t * HH + nt * 16) * HH;
    for (int i = tid; i < 16 * HH; i += 256) {
      int m = i >> 8, k = i & 255;
      tile[m * 264 + k] = src[m * HH + k];
    }
    __syncthreads();
    for (int gi = tid; gi < 512; gi += 256) {
      int ks = gi >> 6, lane = gi & 63;
      int qq = lane >> 4, cc = lane & 15;
      bf16x8 v;
#pragma unroll
      for (int j = 0; j < 8; ++j) v[j] = f2b(tile[cc * 264 + ks * 32 + qq * 8 + j]);
      *(bf16x8*)&W2g[W2G_OFF(t, nt, ks) + lane * 8] = v;
    }
  } else {                            // Wo (N padded 100->128)
    const int h = wg - 1600;
    const int t = h >> 3, nt = h & 7;
    for (int i = tid; i < 16 * HH; i += 256) {
      int m = i >> 8, k = i & 255;
      int n = nt * 16 + m;
      tile[m * 264 + k] = (n < SS) ? Wo[((size_t)t * SS + n) * HH + k] : 0.f;
    }
    __syncthreads();
    for (int gi = tid; gi < 512; gi += 256) {
      int ks = gi >> 6, lane = gi & 63;
      int qq = lane >> 4, cc = lane & 15;
      bf16x8 v;
#pragma unroll
      for (int j = 0; j < 8; ++j) v[j] = f2b(tile[cc * 264 + ks * 32 + qq * 8 + j]);
      *(bf16x8*)&Wog[WOG_OFF(t, nt, ks) + lane * 8] = v;
    }
  }
}

// Persistent kernel: 256 blocks x 16 waves (4 waves/SIMD for TLP latency
// hiding); block owns 16 batch rows. One 16-col n-tile per wave in GEMM1/2;
// waves 0-7 handle GEMM3 + epilogue. LN stats via LDS atomic adds into
// parity-double-buffered accumulators (one barrier), zeroed one step ahead.
template <int MODE>
__global__ __launch_bounds__(NTHR, 4) void run_kernel(
    const float* __restrict__ s0, const float* __restrict__ prices,
    const float* __restrict__ b1, const float* __restrict__ g1, const float* __restrict__ be1,
    const float* __restrict__ b2, const float* __restrict__ g2, const float* __restrict__ be2,
    const float* __restrict__ bo,
    const float* __restrict__ W1f, const float* __restrict__ W2f, const float* __restrict__ Wof,
    const short* __restrict__ W1g, const short* __restrict__ W2g, const short* __restrict__ Wog,
    float* __restrict__ out) {
  __shared__ short sbuf[MROWS][K1 + 8];   // bf16 s, K-padded
  __shared__ short xb1[MROWS][HH + 8];
  __shared__ short xb2[MROWS][HH + 8];
  __shared__ float st0[2][32];            // [parity][row*2 + {S1,S2}]
  __shared__ float st1[2][32];
  __shared__ float wsum[16];

  const int tid = threadIdx.x;
  const int w = tid >> 6;
  const int lane = tid & 63;
  const int q = lane >> 4;
  const int c16 = lane & 15;
  const int b0 = blockIdx.x * MROWS;

  const int n0 = w * 16 + c16;        // GEMM1/2 n-col for this wave's tile
  const bool g3 = w < 8;              // GEMM3/epilogue participant
  const int col3 = (w & 7) * 16 + c16;
  const bool cvalid = g3 && (col3 < SS);

  for (int j = tid; j < MROWS * (K1 + 8); j += NTHR) ((short*)sbuf)[j] = 0;
  if (tid < 64) {
    ((float*)st0)[tid] = 0.f;
    ((float*)st1)[tid] = 0.f;
  }
  __syncthreads();

  float s_reg[4], pr[4];
#pragma unroll
  for (int r = 0; r < 4; ++r) {
    s_reg[r] = 0.f;
    pr[r] = 0.f;
  }
  if (cvalid) {
#pragma unroll
    for (int r = 0; r < 4; ++r) {
      int row = q * 4 + r;
      s_reg[r] = s0[(size_t)(b0 + row) * SS + col3];
      pr[r] = prices[((size_t)(b0 + row) * TT) * SS + col3];
      sbuf[row][col3] = f2b(s_reg[r]);
    }
  }
  __syncthreads();

  float costreg = 0.f;

  // LN: bias add -> in-wave butterfly over 16 cols -> LDS atomic add of
  // (S1,S2) per row -> barrier -> read stats, normalize, relu, write bf16
  // tile -> barrier. st[par^1] is zeroed here for the NEXT step (safe:
  // its last readers finished >=2 barriers ago).
  auto ln_epi = [&](f32x4& acc, float bv, float gv, float ev,
                    short (*dst)[HH + 8], float (*st)[32], int par) {
    float hv[4], p1[4], p2[4];
#pragma unroll
    for (int r = 0; r < 4; ++r) {
      float v = acc[r] + bv;
      hv[r] = v;
      p1[r] = v;
      p2[r] = v * v;
    }
#pragma unroll
    for (int m = 1; m <= 8; m <<= 1)
#pragma unroll
      for (int r = 0; r < 4; ++r) {
        p1[r] += __shfl_xor(p1[r], m);
        p2[r] += __shfl_xor(p2[r], m);
      }
    if (c16 == 0) {
#pragma unroll
      for (int r = 0; r < 4; ++r) {
        atomicAdd(&st[par][(q * 4 + r) * 2 + 0], p1[r]);
        atomicAdd(&st[par][(q * 4 + r) * 2 + 1], p2[r]);
      }
    }
    bar_lds();
    if (w == 0 && lane < 32) st[par ^ 1][lane] = 0.f;
#pragma unroll
    for (int r = 0; r < 4; ++r) {
      f32x2 sv = *(const f32x2*)&st[par][(q * 4 + r) * 2];
      float mean = sv[0] * (1.f / HH);
      float var = fmaxf(sv[1] * (1.f / HH) - mean * mean, 0.f);
      float rstd = rsqrtf(var + 1e-5f);
      float x = (hv[r] - mean) * rstd * gv + ev;
      dst[q * 4 + r][n0] = f2b(fmaxf(x, 0.f));
    }
    bar_lds();
  };

#pragma unroll 1
  for (int t = 0; t < NSTEP; ++t) {
    const int par = t & 1;
    const float b1v = b1[t * HH + n0], g1v = g1[t * HH + n0], e1v = be1[t * HH + n0];
    const float b2v = b2[t * HH + n0], g2v = g2[t * HH + n0], e2v = be2[t * HH + n0];

    // ===== GEMM1: h1[:, n0-tile] = s @ W1[t].T =====
    bf16x8 w1f[4];
#pragma unroll
    for (int ks = 0; ks < 4; ++ks) {
      if (MODE == 0) {
        w1f[ks] = *(const bf16x8*)&W1g[W1G_OFF(t, w, ks) + lane * 8];
      } else {
        w1f[ks] = ldpad(W1f + ((size_t)t * HH + n0) * SS, ks * 32 + q * 8, SS);
      }
    }
    f32x4 acc = (f32x4){0.f, 0.f, 0.f, 0.f};
    f32x4 accb = (f32x4){0.f, 0.f, 0.f, 0.f};
#pragma unroll
    for (int ks = 0; ks < 2; ++ks) {
      bf16x8 a = *(const bf16x8*)&sbuf[c16][ks * 32 + q * 8];
      acc = MFMA(a, w1f[ks], acc);
    }
#pragma unroll
    for (int ks = 2; ks < 4; ++ks) {
      bf16x8 a = *(const bf16x8*)&sbuf[c16][ks * 32 + q * 8];
      accb = MFMA(a, w1f[ks], accb);
    }
    acc = acc + accb;

    ln_epi(acc, b1v, g1v, e1v, xb1, st0, par);

    // ===== GEMM2: h2[:, n0-tile] = x1 @ W2[t].T =====
    bf16x8 w2f[8];
#pragma unroll
    for (int ks = 0; ks < 8; ++ks) {
      if (MODE == 0) {
        w2f[ks] = *(const bf16x8*)&W2g[W2G_OFF(t, w, ks) + lane * 8];
      } else {
        w2f[ks] = cvt8(W2f + ((size_t)t * HH + n0) * HH + ks * 32 + q * 8);
      }
    }
    acc = (f32x4){0.f, 0.f, 0.f, 0.f};
    accb = (f32x4){0.f, 0.f, 0.f, 0.f};
#pragma unroll
    for (int ks = 0; ks < 4; ++ks) {
      bf16x8 a = *(const bf16x8*)&xb1[c16][ks * 32 + q * 8];
      acc = MFMA(a, w2f[ks], acc);
    }
#pragma unroll
    for (int ks = 4; ks < 8; ++ks) {
      bf16x8 a = *(const bf16x8*)&xb1[c16][ks * 32 + q * 8];
      accb = MFMA(a, w2f[ks], accb);
    }
    acc = acc + accb;

    ln_epi(acc, b2v, g2v, e2v, xb2, st1, par);

    // ===== GEMM3 (waves 0-7): o[:, col3-tile] = x2 @ Wo[t].T =====
    f32x4 a3 = (f32x4){0.f, 0.f, 0.f, 0.f};
    if (g3) {
      bf16x8 wof[8];
#pragma unroll
      for (int ks = 0; ks < 8; ++ks) {
        if (MODE == 0) {
          wof[ks] = *(const bf16x8*)&Wog[WOG_OFF(t, w & 7, ks) + lane * 8];
        } else {
          if (col3 < SS) {
            wof[ks] = cvt8(Wof + ((size_t)t * SS + col3) * HH + ks * 32 + q * 8);
          } else {
            bf16x8 z = {0, 0, 0, 0, 0, 0, 0, 0};
            wof[ks] = z;
          }
        }
      }
      f32x4 a3b = (f32x4){0.f, 0.f, 0.f, 0.f};
#pragma unroll
      for (int ks = 0; ks < 4; ++ks) {
        bf16x8 a = *(const bf16x8*)&xb2[c16][ks * 32 + q * 8];
        a3 = MFMA(a, wof[ks], a3);
      }
#pragma unroll
      for (int ks = 4; ks < 8; ++ks) {
        bf16x8 a = *(const bf16x8*)&xb2[c16][ks * 32 + q * 8];
        a3b = MFMA(a, wof[ks], a3b);
      }
      a3 = a3 + a3b;
    }

    // ===== epilogue (waves 0-7): a=min(o+bo,s); cost; s-=a; prices t+1 =====
    if (cvalid) {
      const float bov = bo[t * SS + col3];
#pragma unroll
      for (int r = 0; r < 4; ++r) {
        float o = a3[r] + bov;
        float a = fminf(o, s_reg[r]);
        float pa = pr[r] * a;
        costreg += pa + 0.01f * pa * pa;
        s_reg[r] -= a;
        sbuf[q * 4 + r][col3] = f2b(s_reg[r]);
      }
#pragma unroll
      for (int r = 0; r < 4; ++r)
        pr[r] = prices[((size_t)(b0 + q * 4 + r) * TT + t + 1) * SS + col3];
    }
    bar_lds();
  }

  // ===== terminal: cost += p_T*s + 0.01*(p_T*s)^2 =====
#pragma unroll
  for (int r = 0; r < 4; ++r) {
    float pa = pr[r] * s_reg[r];
    costreg += pa + 0.01f * pa * pa;
  }
#pragma unroll
  for (int m = 1; m < 64; m <<= 1) costreg += __shfl_xor(costreg, m);
  if (lane == 0) wsum[w] = costreg;
  __syncthreads();
  if (tid == 0) {
    float tot = 0.f;
#pragma unroll
    for (int i = 0; i < 16; ++i) tot += wsum[i];
    atomicAdd(out, tot * (1.f / NBATCH));
  }
}

extern "C" void kernel_launch(void* const* d_in, const int* in_sizes, int n_in,
                              void* d_out, int out_size, void* d_ws, size_t ws_size,
                              hipStream_t stream) {
  const float* s0 = (const float*)d_in[0];
  const float* prices = (const float*)d_in[1];
  const float* W1 = (const float*)d_in[2];
  const float* b1 = (const float*)d_in[3];
  const float* g1 = (const float*)d_in[4];
  const float* be1 = (const float*)d_in[5];
  const float* W2 = (const float*)d_in[6];
  const float* b2 = (const float*)d_in[7];
  const float* g2 = (const float*)d_in[8];
  const float* be2 = (const float*)d_in[9];
  const float* Wo = (const float*)d_in[10];
  const float* bo = (const float*)d_in[11];
  float* out = (float*)d_out;

  const size_t need = (N_W1G + N_W2G + N_WOG) * sizeof(short);

  if (ws_size >= need) {
    short* W1g = (short*)d_ws;
    short* W2g = W1g + N_W1G;
    short* Wog = W2g + N_W2G;
    prep<<<dim3(2000), dim3(256), 0, stream>>>(W1, b1, W2, Wo, W1g, W2g, Wog, out);
    run_kernel<0><<<dim3(NBLK), dim3(NTHR), 0, stream>>>(
        s0, prices, b1, g1, be1, b2, g2, be2, bo,
        W1, W2, Wo, W1g, W2g, Wog, out);
  } else {
    zero_out<<<dim3(1), dim3(64), 0, stream>>>(out);
    run_kernel<1><<<dim3(NBLK), dim3(NTHR), 0, stream>>>(
        s0, prices, b1, g1, be1, b2, g2, be2, bo,
        W1, W2, Wo, (const short*)nullptr, (const short*)nullptr, (const short*)nullptr, out);
  }
}